// Round 25
// baseline (233.388 us; speedup 1.0000x reference)
//
#include <hip/hip_runtime.h>
#include <stdint.h>

#define BB 32
#define CC 3
#define LL 512
#define EE 512
#define NBC (BB*CC)

// output offsets (floats)
#define O2_OFF ((size_t)NBC*LL*LL)
#define O3_OFF (O2_OFF + (size_t)NBC*LL*EE)

// ws layout (bytes): small scratch < 512KB; fast-path buffers beyond
#define WSB_QX    0                       // 96*512*4 = 196608 (fallback path only)
#define WSB_H     196608                  // 196608
#define WSB_W     442368                  // 96*4
#define WSB_ADIFF ((size_t)512*1024)
#define ADIFF_BYTES ((size_t)NBC*LL*LL*2)     // 48MiB
#define WSB_X0T   (WSB_ADIFF + ADIFF_BYTES)
#define WS_FAST_NEED (WSB_X0T + ADIFF_BYTES)  // ~96.5MB

#define NEC 16   // e-chunks in k0p

typedef short bf16x8 __attribute__((ext_vector_type(8)));
typedef float f32x4  __attribute__((ext_vector_type(4)));
typedef unsigned short u16x8 __attribute__((ext_vector_type(8)));

__device__ __forceinline__ float wred_sum(float v){
#pragma unroll
  for (int m = 32; m >= 1; m >>= 1) v += __shfl_xor(v, m, 64);
  return v;
}
__device__ __forceinline__ float wred_max(float v){
#pragma unroll
  for (int m = 32; m >= 1; m >>= 1) v = fmaxf(v, __shfl_xor(v, m, 64));
  return v;
}
__device__ __forceinline__ void f4ma(float4& a, float s, const float4& b){
  a.x = fmaf(s, b.x, a.x); a.y = fmaf(s, b.y, a.y);
  a.z = fmaf(s, b.z, a.z); a.w = fmaf(s, b.w, a.w);
}
__device__ __forceinline__ float4 f4sub(const float4& a, const float4& b){
  return make_float4(a.x-b.x, a.y-b.y, a.z-b.z, a.w-b.w);
}
__device__ __forceinline__ unsigned short f2bf(float x){
  unsigned u = __float_as_uint(x);
  return (unsigned short)((u + 0x7FFFu + ((u >> 16) & 1u)) >> 16);
}
__device__ __forceinline__ float bf2f(unsigned short h){
  return __uint_as_float(((unsigned)h) << 16);
}
__device__ __forceinline__ void split1(float v, unsigned short& hi, unsigned short& lo){
  hi = f2bf(v);
  lo = f2bf(v - bf2f(hi));
}
// non-temporal stores (write-only data downstream: bypass cache allocate)
__device__ __forceinline__ void st_nt_f4(float* p, float4 v){
  f32x4 w; w[0]=v.x; w[1]=v.y; w[2]=v.z; w[3]=v.w;
  __builtin_nontemporal_store(w, reinterpret_cast<f32x4*>(p));
}
__device__ __forceinline__ void st_nt_f(float* p, float v){
  __builtin_nontemporal_store(v, p);
}

// ============================================================================
// conv2m: merged [z0: adiff only (-I folded) | z1: x0t | k0p partials].
// R24-VERBATIM (proven pass).
// ============================================================================
__global__ __launch_bounds__(512) void conv2m(
    const float* __restrict__ A0, const float* __restrict__ x0,
    const float* __restrict__ u0,
    const float* __restrict__ t0, const float* __restrict__ t1,
    const float* __restrict__ Qw, const float* __restrict__ Kw,
    const float* __restrict__ Tw,
    char* __restrict__ adiff, char* __restrict__ x0t,
    float* __restrict__ P)
{
  const int bid = blockIdx.x;
  const int t = threadIdx.x;
  __shared__ float T[64][65];                   // z1
  __shared__ float vb[4][4][32];                // k0p

  if (bid < 768) {
    // ---------- z0: adiff only; 16 rows x 4-float chunks ----------
    const int bc = bid >> 3, tile = bid & 7;
    const int r0 = tile*64;
    const size_t abase = (size_t)bc*LL*LL;
    char* ad = adiff + (size_t)bc*LL*LL*2;
    const int q4 = t & 127, rg = t >> 7;       // 4-float chunk; 4 row-groups
    const int base = r0 + rg*16;
    float4 prev = *reinterpret_cast<const float4*>(A0 + abase + (size_t)base*LL + q4*4);
#pragma unroll 4
    for (int i = 0; i < 16; ++i) {
      int gr = base + i;
      float4 cur;
      if (gr + 1 < LL)
        cur = *reinterpret_cast<const float4*>(A0 + abase + (size_t)(gr+1)*LL + q4*4);
      else cur = prev;
      float4 d;
      if (gr < LL-1) d = f4sub(cur, prev);
      else           d = make_float4(0.f,0.f,0.f,0.f);
      // fold -I into adiff; row 511 -> -e511. Branchless on NAMED members
      // (runtime float4 indexing is UB; caused r4/r5/r6/r21's 5.3125 failures).
      if ((gr >> 2) == q4) {
        int e = gr & 3;
        d.x -= (e == 0) ? 1.0f : 0.0f;
        d.y -= (e == 1) ? 1.0f : 0.0f;
        d.z -= (e == 2) ? 1.0f : 0.0f;
        d.w -= (e == 3) ? 1.0f : 0.0f;
      }
      ushort4 pk;
      pk.x = f2bf(d.x); pk.y = f2bf(d.y); pk.z = f2bf(d.z); pk.w = f2bf(d.w);
      *reinterpret_cast<ushort4*>(ad + (size_t)gr*1024 + q4*8) = pk;
      prev = cur;
    }
  } else if (bid < 1536) {
    // ---------- z1: x0t transpose (deferred single 16B stores) ----------
    const int bid1 = bid - 768;
    const int bc = bid1 >> 3, tile = bid1 & 7;
    const int m0 = tile*64;
    const size_t xbase = (size_t)bc*LL*EE;
    char* xt = x0t + (size_t)bc*LL*EE*2;
    u16x8 outs[8];
#pragma unroll
    for (int ech = 0; ech < 8; ++ech) {
      const int e0 = ech*64;
      {
        int ml = t >> 3, seg = t & 7;
        const float* src = x0 + xbase + (size_t)(m0+ml)*EE + e0 + seg*8;
        float4 v0 = *reinterpret_cast<const float4*>(src);
        float4 v1 = *reinterpret_cast<const float4*>(src+4);
        T[ml][seg*8+0]=v0.x; T[ml][seg*8+1]=v0.y; T[ml][seg*8+2]=v0.z; T[ml][seg*8+3]=v0.w;
        T[ml][seg*8+4]=v1.x; T[ml][seg*8+5]=v1.y; T[ml][seg*8+6]=v1.z; T[ml][seg*8+7]=v1.w;
      }
      __syncthreads();
      {
        int el = t >> 3, c3 = t & 7;
        int mb = c3*8;
        u16x8 p;
        p[0]=f2bf(T[mb+0][el]); p[1]=f2bf(T[mb+1][el]);
        p[2]=f2bf(T[mb+2][el]); p[3]=f2bf(T[mb+3][el]);
        p[4]=f2bf(T[mb+4][el]); p[5]=f2bf(T[mb+5][el]);
        p[6]=f2bf(T[mb+6][el]); p[7]=f2bf(T[mb+7][el]);
        outs[ech] = p;
      }
      __syncthreads();
    }
    {
      int el = t >> 3, c3 = t & 7;
#pragma unroll
      for (int ech = 0; ech < 8; ++ech) {
        int eg = ech*64 + el;
        *reinterpret_cast<u16x8*>(xt + (size_t)eg*1024 + (size_t)(m0 + c3*8)*2) = outs[ech];
      }
    }
  } else {
    // ---------- k0p: split-K partial matvecs ----------
    const int idx = bid - 1536;
    const int bg = idx & 7;
    const int rem = idx >> 3;
    const int c  = rem % 3;
    const int ec = rem / 3;
    const int b0 = bg*4;
    const int e0 = ec*32;
    const int f  = t;
    {
      int vec = f >> 7, j = (f >> 5) & 3, e = f & 31;
      int bb = b0 + j;
      float v;
      if      (vec == 0) v = t0[bb*EE + e0 + e];
      else if (vec == 1) v = t1[bb*EE + e0 + e];
      else if (vec == 2) v = x0[((size_t)(bb*CC + c)*LL + (LL-1))*EE + e0 + e];
      else               v = u0[(size_t)(bb*CC + c)*EE + e0 + e];
      vb[vec][j][e] = v;
    }
    __syncthreads();
    const float* twp = Tw + (size_t)c*EE*EE + (size_t)e0*EE + f;
    const float* qwp = Qw + (size_t)c*EE*EE + (size_t)e0*EE + f;
    const float* kwp = Kw + (size_t)c*EE*EE + (size_t)e0*EE + f;
    float aT0[4]={0,0,0,0}, aT1[4]={0,0,0,0}, aQ[4]={0,0,0,0}, aK[4]={0,0,0,0};
#pragma unroll 8
    for (int e = 0; e < 32; ++e) {
      float wt = twp[(size_t)e*EE];
      float wq = qwp[(size_t)e*EE];
      float wk = kwp[(size_t)e*EE];
#pragma unroll
      for (int j = 0; j < 4; ++j) {
        aT0[j] = fmaf(vb[0][j][e], wt, aT0[j]);
        aT1[j] = fmaf(vb[1][j][e], wt, aT1[j]);
        aQ[j]  = fmaf(vb[2][j][e], wq, aQ[j]);
        aK[j]  = fmaf(vb[3][j][e], wk, aK[j]);
      }
    }
#pragma unroll
    for (int j = 0; j < 4; ++j) {
      int cb = c*BB + b0 + j;
      P[(((size_t)0*NEC + ec)*96 + cb)*EE + f] = aT0[j];
      P[(((size_t)1*NEC + ec)*96 + cb)*EE + f] = aT1[j];
      P[(((size_t)2*NEC + ec)*96 + cb)*EE + f] = aQ[j];
      P[(((size_t)3*NEC + ec)*96 + cb)*EE + f] = aK[j];
    }
  }
}

// ============ k0c: combine partials -> gt, ws_w (R24-VERBATIM, proven) ============
__global__ __launch_bounds__(512) void k0c(
    const float* __restrict__ P,
    const float* __restrict__ Qb, const float* __restrict__ Kb,
    float* __restrict__ gtbuf, float* __restrict__ ws_w)
{
  const int bc = blockIdx.x;
  const int b = bc / CC, c = bc % CC;
  const int cb = c*BB + b;
  const int f = threadIdx.x;
  const int wid = f >> 6, lane = f & 63;
  __shared__ float red[8][3];
  float aT0=0.f, aT1=0.f, aQ=0.f, aK=0.f;
#pragma unroll
  for (int ec = 0; ec < NEC; ++ec) {
    aT0 += P[(((size_t)0*NEC + ec)*96 + cb)*EE + f];
    aT1 += P[(((size_t)1*NEC + ec)*96 + cb)*EE + f];
    aQ  += P[(((size_t)2*NEC + ec)*96 + cb)*EE + f];
    aK  += P[(((size_t)3*NEC + ec)*96 + cb)*EE + f];
  }
  float Qv = aQ*aT0 + Qb[c*EE + f];
  float Kv = aK*aT1 + Kb[c*EE + f];
  gtbuf[(size_t)cb*EE + f] = Qv*Kv*aT1;
  float pn = wred_sum(aT0*aT1);
  float p0 = wred_sum(aT0*aT0);
  float p1 = wred_sum(aT1*aT1);
  if (lane == 0) { red[wid][0]=pn; red[wid][1]=p0; red[wid][2]=p1; }
  __syncthreads();
  if (f == 0) {
    float sn=0.f, s0=0.f, s1=0.f;
    for (int i=0;i<8;++i){ sn+=red[i][0]; s0+=red[i][1]; s1+=red[i][2]; }
    ws_w[bc] = sn / sqrtf(s0 + s1);
  }
}

// ============ k1: split-precision MFMA h (R9-VERBATIM, proven) ============
__global__ __launch_bounds__(256) void k1_h(
    const float* __restrict__ Vw, const float* __restrict__ gtbuf,
    float* __restrict__ ws_h)
{
  const int nt = blockIdx.x;
  const int c  = blockIdx.y;
  const int n0 = nt*128;
  const int t = threadIdx.x, lane = t & 63, w = t >> 6;
  __shared__ __align__(16) char AgtH[32*1024];
  __shared__ __align__(16) char AgtL[32*1024];
  __shared__ __align__(16) char BvH[128*128];
  __shared__ __align__(16) char BvL[128*128];
  {
    int row = t >> 3, sl = t & 7;
    const float* src = gtbuf + ((size_t)(c*BB + row))*EE + sl*64;
#pragma unroll
    for (int c3 = 0; c3 < 8; ++c3) {
      float4 a = *reinterpret_cast<const float4*>(src + c3*8);
      float4 b = *reinterpret_cast<const float4*>(src + c3*8 + 4);
      ushort4 h0,h1,l0,l1;
      split1(a.x,h0.x,l0.x); split1(a.y,h0.y,l0.y); split1(a.z,h0.z,l0.z); split1(a.w,h0.w,l0.w);
      split1(b.x,h1.x,l1.x); split1(b.y,h1.y,l1.y); split1(b.z,h1.z,l1.z); split1(b.w,h1.w,l1.w);
      int off = row*1024 + sl*128 + ((c3 ^ (row & 7)) << 4);
      *reinterpret_cast<ushort4*>(AgtH + off)     = h0;
      *reinterpret_cast<ushort4*>(AgtH + off + 8) = h1;
      *reinterpret_cast<ushort4*>(AgtL + off)     = l0;
      *reinterpret_cast<ushort4*>(AgtL + off + 8) = l1;
    }
  }
  f32x4 acc[2][2];
#pragma unroll
  for (int mi=0; mi<2; ++mi)
#pragma unroll
    for (int ni=0; ni<2; ++ni) acc[mi][ni] = (f32x4){0.f,0.f,0.f,0.f};

  for (int kk = 0; kk < 8; ++kk) {
    __syncthreads();
    {
      int nl = t >> 1, half = t & 1;
      const float* src = Vw + (size_t)c*EE*EE + (size_t)(n0+nl)*EE + kk*64 + half*32;
#pragma unroll
      for (int q = 0; q < 4; ++q) {
        float4 a = *reinterpret_cast<const float4*>(src + q*8);
        float4 b = *reinterpret_cast<const float4*>(src + q*8 + 4);
        int c3 = half*4 + q;
        ushort4 h0,h1,l0,l1;
        split1(a.x,h0.x,l0.x); split1(a.y,h0.y,l0.y); split1(a.z,h0.z,l0.z); split1(a.w,h0.w,l0.w);
        split1(b.x,h1.x,l1.x); split1(b.y,h1.y,l1.y); split1(b.z,h1.z,l1.z); split1(b.w,h1.w,l1.w);
        int off = nl*128 + ((c3 ^ (nl & 7)) << 4);
        *reinterpret_cast<ushort4*>(BvH + off)     = h0;
        *reinterpret_cast<ushort4*>(BvH + off + 8) = h1;
        *reinterpret_cast<ushort4*>(BvL + off)     = l0;
        *reinterpret_cast<ushort4*>(BvL + off + 8) = l1;
      }
    }
    __syncthreads();
    bf16x8 afH[2][2], afL[2][2], bfH[2][2], bfL[2][2];
#pragma unroll
    for (int mi=0; mi<2; ++mi)
#pragma unroll
      for (int ks=0; ks<2; ++ks) {
        int row = mi*16 + (lane & 15);
        int c3 = ks*4 + (lane >> 4);
        int off = row*1024 + kk*128 + ((c3 ^ (row & 7)) << 4);
        afH[mi][ks] = *reinterpret_cast<const bf16x8*>(AgtH + off);
        afL[mi][ks] = *reinterpret_cast<const bf16x8*>(AgtL + off);
      }
#pragma unroll
    for (int ni=0; ni<2; ++ni)
#pragma unroll
      for (int ks=0; ks<2; ++ks) {
        int n = w*32 + ni*16 + (lane & 15);
        int c3 = ks*4 + (lane >> 4);
        int off = n*128 + ((c3 ^ (n & 7)) << 4);
        bfH[ni][ks] = *reinterpret_cast<const bf16x8*>(BvH + off);
        bfL[ni][ks] = *reinterpret_cast<const bf16x8*>(BvL + off);
      }
#pragma unroll
    for (int mi=0; mi<2; ++mi)
#pragma unroll
      for (int ni=0; ni<2; ++ni)
#pragma unroll
        for (int ks=0; ks<2; ++ks) {
          acc[mi][ni] = __builtin_amdgcn_mfma_f32_16x16x32_bf16(afH[mi][ks], bfH[ni][ks], acc[mi][ni], 0, 0, 0);
          acc[mi][ni] = __builtin_amdgcn_mfma_f32_16x16x32_bf16(afH[mi][ks], bfL[ni][ks], acc[mi][ni], 0, 0, 0);
          acc[mi][ni] = __builtin_amdgcn_mfma_f32_16x16x32_bf16(afL[mi][ks], bfH[ni][ks], acc[mi][ni], 0, 0, 0);
        }
  }
#pragma unroll
  for (int mi=0; mi<2; ++mi)
#pragma unroll
    for (int ni=0; ni<2; ++ni)
#pragma unroll
      for (int r=0; r<4; ++r) {
        int b = mi*16 + (lane >> 4)*4 + r;
        int e = n0 + w*32 + ni*16 + (lane & 15);
        ws_h[((size_t)(b*CC + c))*EE + e] = acc[mi][ni][r];
      }
}

// ============ k2f: merged softmax+stats; NOW ALSO writes out2 row 511 (exact f32) ============
__global__ __launch_bounds__(512) void k2f(
    const float* __restrict__ A0, const float* __restrict__ x0,
    const float* __restrict__ u0,
    const float* __restrict__ ws_h, const float* __restrict__ ws_w,
    float* __restrict__ out1, float* __restrict__ out2, float* __restrict__ out3)
{
  const int bc = blockIdx.x;
  const int tid = threadIdx.x, wid = tid >> 6, lane = tid & 63;
  __shared__ __align__(16) float hb[EE], sb[LL], a0r0[LL], a0r3[LL];
  __shared__ float red[8];
  __shared__ float partl[4][12][128];
  const size_t abase = (size_t)bc*LL*LL;
  const size_t xbase = (size_t)bc*LL*EE;
  hb[tid]   = ws_h[(size_t)bc*EE + tid];
  a0r0[tid] = A0[abase + tid];
  a0r3[tid] = A0[abase + (size_t)(LL-1)*LL + tid];
  __syncthreads();
  const float4 h0 = *reinterpret_cast<const float4*>(&hb[lane*8]);
  const float4 h1 = *reinterpret_cast<const float4*>(&hb[lane*8+4]);
  for (int l = wid; l < LL; l += 8) {
    const float4* xr = reinterpret_cast<const float4*>(x0 + xbase + (size_t)l*EE);
    float4 v0 = xr[lane*2], v1 = xr[lane*2+1];
    float acc = v0.x*h0.x + v0.y*h0.y + v0.z*h0.z + v0.w*h0.w
              + v1.x*h1.x + v1.y*h1.y + v1.z*h1.z + v1.w*h1.w;
    acc = wred_sum(acc);
    if (lane == 0) sb[l] = acc;
  }
  __syncthreads();
  float v = sb[tid];
  float mx = wred_max(v);
  if (lane == 0) red[wid] = mx;
  __syncthreads();
  mx = red[0];
#pragma unroll
  for (int i = 1; i < 8; ++i) mx = fmaxf(mx, red[i]);
  float ev = __expf(v - mx);
  float sm = wred_sum(ev);
  __syncthreads();
  if (lane == 0) red[wid] = sm;
  __syncthreads();
  float tot = 0.f;
#pragma unroll
  for (int i = 0; i < 8; ++i) tot += red[i];
  float qk = ev / tot;
  sb[tid] = qk;
  st_nt_f(out1 + abase + (size_t)(LL-1)*LL + tid, qk - a0r0[tid]);
  __syncthreads();
  const int mg = tid >> 7, cg = tid & 127;
  float4 aq = make_float4(0,0,0,0), a0s = make_float4(0,0,0,0), a3s = make_float4(0,0,0,0);
#pragma unroll 4
  for (int i = 0; i < 128; ++i) {
    int m = mg*128 + i;
    float4 xv = *reinterpret_cast<const float4*>(x0 + xbase + (size_t)m*EE + cg*4);
    float qm = sb[m], z0 = a0r0[m], z3 = a0r3[m];
    f4ma(aq, qm, xv); f4ma(a0s, z0, xv); f4ma(a3s, z3, xv);
  }
#pragma unroll
  for (int k = 0; k < 4; ++k) {
    partl[mg][0+k][cg] = (&aq.x)[k];
    partl[mg][4+k][cg] = (&a0s.x)[k];
    partl[mg][8+k][cg] = (&a3s.x)[k];
  }
  __syncthreads();
  if (mg == 0) {
    float wv = ws_w[bc];
    float4 uv  = *reinterpret_cast<const float4*>(u0 + (size_t)bc*EE + cg*4);
    float4 x51 = *reinterpret_cast<const float4*>(x0 + xbase + (size_t)(LL-1)*EE + cg*4);
    float4 qx4, o3;
#pragma unroll
    for (int k = 0; k < 4; ++k) {
      float q = 0.f, y0 = 0.f, y3 = 0.f;
#pragma unroll
      for (int g = 0; g < 4; ++g) {
        q  += partl[g][0+k][cg];
        y0 += partl[g][4+k][cg];
        y3 += partl[g][8+k][cg];
      }
      (&qx4.x)[k] = q;
      (&o3.x)[k] = wv * ((y3 - y0 + q) * (1.f/(float)LL) - (&uv.x)[k]);
    }
    // out2 row 511 = qx - x0[511] (exact f32); k3_bf skips this row
    st_nt_f4(out2 + xbase + (size_t)(LL-1)*EE + cg*4, f4sub(qx4, x51));
    st_nt_f4(out3 + (size_t)bc*EE + cg*4, o3);
  }
}

// ============ k3_bf: (D-I)@x0 + balanced out1 reconstruction; row 511 skipped ============
#define ASTR 80
__global__ __launch_bounds__(256) void k3_bf(
    const char* __restrict__ adiff, const char* __restrict__ x0t,
    const float* __restrict__ A0,
    float* __restrict__ out1, float* __restrict__ out2)
{
  const int bc = blockIdx.y;
  const int rt = blockIdx.x >> 2, nt = blockIdx.x & 3;
  const int r0 = rt*128, n0b = nt*128;
  const int t = threadIdx.x;
  const int lane = t & 63, wid = t >> 6;
  const int wr = wid >> 1, wc = wid & 1;
  __shared__ __align__(16) char As[128*ASTR];
  __shared__ __align__(16) char Bs[128*ASTR];
  __shared__ __align__(16) float zr[LL];
  const char* ad = adiff + (size_t)bc*LL*LL*2;
  const char* xt = x0t  + (size_t)bc*LL*EE*2;
  const size_t abase = (size_t)bc*LL*LL;
  const size_t xbase = (size_t)bc*LL*EE;
  zr[t]       = A0[abase + t];
  zr[t + 256] = A0[abase + t + 256];
  f32x4 acc[4][4];
#pragma unroll
  for (int mi=0; mi<4; ++mi)
#pragma unroll
    for (int ni=0; ni<4; ++ni) acc[mi][ni] = (f32x4){0.f,0.f,0.f,0.f};

  for (int k0 = 0; k0 < LL; k0 += 32) {
    __syncthreads();
#pragma unroll
    for (int i = 0; i < 2; ++i) {
      int idx = i*256 + t;
      int row = idx >> 2, c = idx & 3;
      int4 v = *reinterpret_cast<const int4*>(ad + (size_t)(r0+row)*1024 + k0*2 + c*16);
      *reinterpret_cast<int4*>(As + row*ASTR + c*16) = v;
    }
#pragma unroll
    for (int i = 0; i < 2; ++i) {
      int idx = i*256 + t;
      int n = idx >> 2, c = idx & 3;
      int4 v = *reinterpret_cast<const int4*>(xt + (size_t)(n0b+n)*1024 + k0*2 + c*16);
      int kb = (c*16) ^ (((n >> 2) & 3) << 4);
      *reinterpret_cast<int4*>(Bs + n*ASTR + kb) = v;
    }
    __syncthreads();
    bf16x8 af[4], bfv[4];
#pragma unroll
    for (int mi=0; mi<4; ++mi) {
      int row = wr*64 + mi*16 + (lane & 15);
      af[mi] = *reinterpret_cast<const bf16x8*>(As + row*ASTR + ((lane>>4)*16));
    }
#pragma unroll
    for (int ni=0; ni<4; ++ni) {
      int n = wc*64 + ni*16 + (lane & 15);
      int kb = ((lane>>4)*16) ^ (((n >> 2) & 3) << 4);
      bfv[ni] = *reinterpret_cast<const bf16x8*>(Bs + n*ASTR + kb);
    }
#pragma unroll
    for (int mi=0; mi<4; ++mi)
#pragma unroll
      for (int ni=0; ni<4; ++ni)
        acc[mi][ni] = __builtin_amdgcn_mfma_f32_16x16x32_bf16(af[mi], bfv[ni], acc[mi][ni], 0, 0, 0);
    // balanced out1 reconstruction: this block owns slabs where ((k0>>5)&3)==nt
    if (((k0 >> 5) & 3) == nt) {
      const int c4 = (t & 7) * 4;
      const int gcol0 = k0 + c4;
      const float4 zz = *reinterpret_cast<const float4*>(&zr[gcol0]);
#pragma unroll
      for (int rr = 0; rr < 4; ++rr) {
        int row = rr*32 + (t >> 3);
        int gr = r0 + row;
        if (gr < LL-1) {
          ushort4 ap = *reinterpret_cast<const ushort4*>(As + row*ASTR + c4*2);
          float4 o;
          o.x = bf2f(ap.x); o.y = bf2f(ap.y); o.z = bf2f(ap.z); o.w = bf2f(ap.w);
          int e = gr - gcol0;
          o.x += (e == 0) ? 1.0f : 0.0f;
          o.y += (e == 1) ? 1.0f : 0.0f;
          o.z += (e == 2) ? 1.0f : 0.0f;
          o.w += (e == 3) ? 1.0f : 0.0f;
          st_nt_f4(out1 + abase + (size_t)gr*LL + gcol0, f4sub(o, zz));
        }
      }
    }
  }
  // epilogue: out2 = acc; row 511 is written by k2f (skip here)
#pragma unroll
  for (int mi=0; mi<4; ++mi)
#pragma unroll
    for (int r=0; r<4; ++r) {
      int grow = r0 + wr*64 + mi*16 + (lane>>4)*4 + r;
      if (grow >= LL-1) continue;
      const size_t rowoff = xbase + (size_t)grow*EE;
#pragma unroll
      for (int ni=0; ni<4; ++ni) {
        int gcol = n0b + wc*64 + ni*16 + (lane & 15);
        st_nt_f(out2 + rowoff + gcol, acc[mi][ni][r]);
      }
    }
}

// ============ kA_fused + k3_mfma: R3-VERBATIM fallback path ============
__global__ __launch_bounds__(512) void kA_fused(
    const float* __restrict__ A0, const float* __restrict__ x0,
    const float* __restrict__ u0,
    const float* __restrict__ t0, const float* __restrict__ t1,
    const float* __restrict__ Qw, const float* __restrict__ Qb,
    const float* __restrict__ Vw,
    const float* __restrict__ Kw, const float* __restrict__ Kb,
    const float* __restrict__ Tw,
    float* __restrict__ ws_qx, float* __restrict__ out1, float* __restrict__ out3)
{
  const int bc = blockIdx.x;
  const int b = bc / CC, c = bc % CC;
  const int tid = threadIdx.x;
  const int wid = tid >> 6, lane = tid & 63;
  __shared__ __align__(16) float t0v[EE], t1v[EE], xl[EE], uv[EE], gt[EE];
  __shared__ __align__(16) float hb[EE], sb[LL], a0r0[LL], a0r3[LL];
  __shared__ float red[3][8];
  __shared__ float wsh;
  const size_t abase = (size_t)bc*LL*LL;
  const size_t xbase = (size_t)bc*LL*EE;

  t0v[tid] = t0[b*EE + tid];
  t1v[tid] = t1[b*EE + tid];
  xl[tid]  = x0[xbase + (size_t)(LL-1)*EE + tid];
  uv[tid]  = u0[(size_t)bc*EE + tid];
  a0r0[tid] = A0[abase + tid];
  a0r3[tid] = A0[abase + (size_t)(LL-1)*LL + tid];
  __syncthreads();

  const int f = tid;
  const float* twp = Tw + (size_t)c*EE*EE + f;
  const float* qwp = Qw + (size_t)c*EE*EE + f;
  const float* kwp = Kw + (size_t)c*EE*EE + f;
  float aT0 = 0.f, aT1 = 0.f, aQ = 0.f, aK = 0.f;
  for (int e = 0; e < EE; ++e) {
    float wt = twp[(size_t)e*EE];
    aT0 = fmaf(t0v[e], wt, aT0);
    aT1 = fmaf(t1v[e], wt, aT1);
    aQ  = fmaf(xl[e],  qwp[(size_t)e*EE], aQ);
    aK  = fmaf(uv[e],  kwp[(size_t)e*EE], aK);
  }
  float Qv = aQ*aT0 + Qb[c*EE + f];
  float Kv = aK*aT1 + Kb[c*EE + f];
  gt[f] = Qv*Kv*aT1;

  float pn = wred_sum(aT0*aT1);
  float p0 = wred_sum(aT0*aT0);
  float p1 = wred_sum(aT1*aT1);
  if (lane == 0) { red[0][wid]=pn; red[1][wid]=p0; red[2][wid]=p1; }
  __syncthreads();
  if (tid == 0) {
    float sn=0.f, s0=0.f, s1=0.f;
    for (int i=0;i<8;++i){ sn+=red[0][i]; s0+=red[1][i]; s1+=red[2][i]; }
    wsh = sn / sqrtf(s0 + s1);
  }
  {
    const float4 g0 = *reinterpret_cast<const float4*>(&gt[lane*8]);
    const float4 g1 = *reinterpret_cast<const float4*>(&gt[lane*8+4]);
    for (int r = wid; r < EE; r += 8) {
      const float4* vr = reinterpret_cast<const float4*>(Vw + ((size_t)c*EE + r)*EE);
      float4 v0 = vr[lane*2], v1 = vr[lane*2+1];
      float acc = v0.x*g0.x + v0.y*g0.y + v0.z*g0.z + v0.w*g0.w
                + v1.x*g1.x + v1.y*g1.y + v1.z*g1.z + v1.w*g1.w;
      acc = wred_sum(acc);
      if (lane == 0) hb[r] = acc;
    }
  }
  __syncthreads();

  {
    const float4 h0 = *reinterpret_cast<const float4*>(&hb[lane*8]);
    const float4 h1 = *reinterpret_cast<const float4*>(&hb[lane*8+4]);
    for (int l = wid; l < LL; l += 8) {
      const float4* xr = reinterpret_cast<const float4*>(x0 + xbase + (size_t)l*EE);
      float4 v0 = xr[lane*2], v1 = xr[lane*2+1];
      float acc = v0.x*h0.x + v0.y*h0.y + v0.z*h0.z + v0.w*h0.w
                + v1.x*h1.x + v1.y*h1.y + v1.z*h1.z + v1.w*h1.w;
      acc = wred_sum(acc);
      if (lane == 0) sb[l] = acc;
    }
  }
  __syncthreads();

  float v = sb[tid];
  float mx = wred_max(v);
  if (lane == 0) red[0][wid] = mx;
  __syncthreads();
  mx = red[0][0];
#pragma unroll
  for (int i = 1; i < 8; ++i) mx = fmaxf(mx, red[0][i]);
  float ev = __expf(v - mx);
  float sm = wred_sum(ev);
  __syncthreads();
  if (lane == 0) red[0][wid] = sm;
  __syncthreads();
  float tot = 0.f;
#pragma unroll
  for (int i = 0; i < 8; ++i) tot += red[0][i];
  float qk = ev / tot;
  sb[tid] = qk;
  out1[abase + (size_t)(LL-1)*LL + tid] = qk - a0r0[tid];
  __syncthreads();

  float qx=0.f, y0=0.f, y3=0.f;
  for (int m = 0; m < LL; ++m) {
    float xm = x0[xbase + (size_t)m*EE + tid];
    qx = fmaf(sb[m],   xm, qx);
    y0 = fmaf(a0r0[m], xm, y0);
    y3 = fmaf(a0r3[m], xm, y3);
  }
  ws_qx[(size_t)bc*EE + tid] = qx;
  float mean = (y3 - y0 + qx) * (1.f/(float)LL);
  out3[(size_t)bc*EE + tid] = wsh * (mean - uv[tid]);
}

__global__ __launch_bounds__(256) void k3_mfma(
    const float* __restrict__ A0, const float* __restrict__ x0,
    const float* __restrict__ ws_qx,
    float* __restrict__ out1, float* __restrict__ out2)
{
  const int bc = blockIdx.y;
  const int rt = blockIdx.x >> 2, nt = blockIdx.x & 3;
  const int r0 = rt*128, n0b = nt*128;
  const int t = threadIdx.x;
  const int lane = t & 63, wid = t >> 6;
  const int wr = wid >> 1, wc = wid & 1;
  __shared__ __align__(16) char As[128*ASTR];
  __shared__ __align__(16) char Bs[128*ASTR];
  const size_t abase = (size_t)bc*LL*LL;
  const size_t xbase = (size_t)bc*LL*EE;
  f32x4 acc[4][4];
#pragma unroll
  for (int mi=0; mi<4; ++mi)
#pragma unroll
    for (int ni=0; ni<4; ++ni) acc[mi][ni] = (f32x4){0.f,0.f,0.f,0.f};
  const int bkl = (t & 7) * 4;
  const int bn0 = (t >> 3) * 4;
  for (int k0 = 0; k0 < LL; k0 += 32) {
    __syncthreads();
#pragma unroll
    for (int i = 0; i < 4; ++i) {
      int idx = i*256 + t;
      int row = idx >> 3, kq = idx & 7;
      int gr = r0 + row;
      int gr1 = (gr+1 > LL-1) ? (LL-1) : (gr+1);
      float4 va = *reinterpret_cast<const float4*>(A0 + abase + (size_t)gr *LL + k0 + kq*4);
      float4 vb = *reinterpret_cast<const float4*>(A0 + abase + (size_t)gr1*LL + k0 + kq*4);
      ushort4 pk;
      pk.x = f2bf(vb.x - va.x); pk.y = f2bf(vb.y - va.y);
      pk.z = f2bf(vb.z - va.z); pk.w = f2bf(vb.w - va.w);
      *reinterpret_cast<ushort4*>(As + row*ASTR + kq*8) = pk;
      if (nt == 0 && gr < LL-1) {
        float4 az = *reinterpret_cast<const float4*>(A0 + abase + k0 + kq*4);
        float4 o = make_float4(vb.x - az.x - va.x, vb.y - az.y - va.y,
                               vb.z - az.z - va.z, vb.w - az.w - va.w);
        *reinterpret_cast<float4*>(out1 + abase + (size_t)gr*LL + k0 + kq*4) = o;
      }
    }
    {
      float xq[4][4];
#pragma unroll
      for (int i = 0; i < 4; ++i)
        *reinterpret_cast<float4*>(xq[i]) =
          *reinterpret_cast<const float4*>(x0 + xbase + (size_t)(k0+bkl+i)*EE + n0b + bn0);
#pragma unroll
      for (int j = 0; j < 4; ++j) {
        int n = bn0 + j;
        ushort4 pk;
        pk.x = f2bf(xq[0][j]); pk.y = f2bf(xq[1][j]);
        pk.z = f2bf(xq[2][j]); pk.w = f2bf(xq[3][j]);
        int kb = (bkl*2) ^ (((n >> 2) & 3) << 4);
        *reinterpret_cast<ushort4*>(Bs + n*ASTR + kb) = pk;
      }
    }
    __syncthreads();
    bf16x8 af[4], bfv[4];
#pragma unroll
    for (int mi=0; mi<4; ++mi) {
      int row = wr*64 + mi*16 + (lane & 15);
      af[mi] = *reinterpret_cast<const bf16x8*>(As + row*ASTR + ((lane>>4)*16));
    }
#pragma unroll
    for (int ni=0; ni<4; ++ni) {
      int n = wc*64 + ni*16 + (lane & 15);
      int kb = ((lane>>4)*16) ^ (((n >> 2) & 3) << 4);
      bfv[ni] = *reinterpret_cast<const bf16x8*>(Bs + n*ASTR + kb);
    }
#pragma unroll
    for (int mi=0; mi<4; ++mi)
#pragma unroll
      for (int ni=0; ni<4; ++ni)
        acc[mi][ni] = __builtin_amdgcn_mfma_f32_16x16x32_bf16(af[mi], bfv[ni], acc[mi][ni], 0, 0, 0);
  }
#pragma unroll
  for (int mi=0; mi<4; ++mi)
#pragma unroll
    for (int r=0; r<4; ++r) {
      int grow = r0 + wr*64 + mi*16 + (lane>>4)*4 + r;
      const size_t rowoff = xbase + (size_t)grow*EE;
#pragma unroll
      for (int ni=0; ni<4; ++ni) {
        int gcol = n0b + wc*64 + ni*16 + (lane & 15);
        float xv = x0[rowoff + gcol];
        float val;
        if (grow == LL-1) val = ws_qx[(size_t)bc*EE + gcol] - xv;
        else              val = acc[mi][ni][r] - xv;
        out2[rowoff + gcol] = val;
      }
    }
}

extern "C" void kernel_launch(void* const* d_in, const int* in_sizes, int n_in,
                              void* d_out, int out_size, void* d_ws, size_t ws_size,
                              hipStream_t stream)
{
  const float* A0 = (const float*)d_in[0];
  const float* x0 = (const float*)d_in[1];
  const float* u0 = (const float*)d_in[2];
  const float* t0 = (const float*)d_in[3];
  const float* t1 = (const float*)d_in[4];
  const float* Qw = (const float*)d_in[5];
  const float* Qb = (const float*)d_in[6];
  const float* Vw = (const float*)d_in[7];
  // d_in[8] = V_bias: zeros + softmax-invariant; skipped.
  const float* Kw = (const float*)d_in[9];
  const float* Kb = (const float*)d_in[10];
  const float* Tw = (const float*)d_in[11];
  // d_in[12] = T_bias: unused by the reference.

  char*  wsb    = (char*)d_ws;
  float* ws_qx  = (float*)(wsb + WSB_QX);
  float* ws_h   = (float*)(wsb + WSB_H);
  float* ws_w   = (float*)(wsb + WSB_W);

  float* out1 = (float*)d_out;
  float* out2 = out1 + O2_OFF;
  float* out3 = out1 + O3_OFF;
  float* gtbuf = out3;   // out3 region doubles as gt scratch (overwritten by k2f)
  float* pscr  = out2;   // out2 region doubles as k0 partial scratch (overwritten by k3_bf)

  const bool fast = ws_size >= WS_FAST_NEED;

  if (fast) {
    char* adiff = wsb + WSB_ADIFF;
    char* x0t   = wsb + WSB_X0T;
    conv2m<<<1920, 512, 0, stream>>>(A0, x0, u0, t0, t1, Qw, Kw, Tw,
                                     adiff, x0t, pscr);
    k0c<<<NBC, 512, 0, stream>>>(pscr, Qb, Kb, gtbuf, ws_w);
    k1_h<<<dim3(4, 3), 256, 0, stream>>>(Vw, gtbuf, ws_h);
    k2f<<<NBC, 512, 0, stream>>>(A0, x0, u0, ws_h, ws_w, out1, out2, out3);
    k3_bf<<<dim3(16, NBC), 256, 0, stream>>>(adiff, x0t, A0, out1, out2);
  } else {
    kA_fused<<<NBC, 512, 0, stream>>>(A0, x0, u0, t0, t1, Qw, Qb, Vw, Kw, Kb, Tw,
                                      ws_qx, out1, out3);
    k3_mfma<<<dim3(16, NBC), 256, 0, stream>>>(A0, x0, ws_qx, out1, out2);
  }
}

// Round 26
// 230.754 us; speedup vs baseline: 1.0114x; 1.0114x over previous
//
#include <hip/hip_runtime.h>
#include <stdint.h>

#define BB 32
#define CC 3
#define LL 512
#define EE 512
#define NBC (BB*CC)

// output offsets (floats)
#define O2_OFF ((size_t)NBC*LL*LL)
#define O3_OFF (O2_OFF + (size_t)NBC*LL*EE)

// ws layout (bytes): small scratch < 512KB; fast-path buffers beyond
#define WSB_QX    0                       // 96*512*4 = 196608 (fallback path only)
#define WSB_H     196608                  // 196608
#define WSB_W     442368                  // 96*4
#define WSB_ADIFF ((size_t)512*1024)
#define ADIFF_BYTES ((size_t)NBC*LL*LL*2)     // 48MiB
#define WS_FAST_NEED (WSB_ADIFF + ADIFF_BYTES)  // ~48.5MB

#define NEC 16   // e-chunks in k0p

typedef short bf16x8 __attribute__((ext_vector_type(8)));
typedef float f32x4  __attribute__((ext_vector_type(4)));
typedef unsigned short u16x8 __attribute__((ext_vector_type(8)));

__device__ __forceinline__ float wred_sum(float v){
#pragma unroll
  for (int m = 32; m >= 1; m >>= 1) v += __shfl_xor(v, m, 64);
  return v;
}
__device__ __forceinline__ float wred_max(float v){
#pragma unroll
  for (int m = 32; m >= 1; m >>= 1) v = fmaxf(v, __shfl_xor(v, m, 64));
  return v;
}
__device__ __forceinline__ void f4ma(float4& a, float s, const float4& b){
  a.x = fmaf(s, b.x, a.x); a.y = fmaf(s, b.y, a.y);
  a.z = fmaf(s, b.z, a.z); a.w = fmaf(s, b.w, a.w);
}
__device__ __forceinline__ float4 f4sub(const float4& a, const float4& b){
  return make_float4(a.x-b.x, a.y-b.y, a.z-b.z, a.w-b.w);
}
__device__ __forceinline__ unsigned short f2bf(float x){
  unsigned u = __float_as_uint(x);
  return (unsigned short)((u + 0x7FFFu + ((u >> 16) & 1u)) >> 16);
}
__device__ __forceinline__ float bf2f(unsigned short h){
  return __uint_as_float(((unsigned)h) << 16);
}
__device__ __forceinline__ void split1(float v, unsigned short& hi, unsigned short& lo){
  hi = f2bf(v);
  lo = f2bf(v - bf2f(hi));
}
// non-temporal stores (write-only data downstream: bypass cache allocate)
__device__ __forceinline__ void st_nt_f4(float* p, float4 v){
  f32x4 w; w[0]=v.x; w[1]=v.y; w[2]=v.z; w[3]=v.w;
  __builtin_nontemporal_store(w, reinterpret_cast<f32x4*>(p));
}
__device__ __forceinline__ void st_nt_f(float* p, float v){
  __builtin_nontemporal_store(v, p);
}

// ============================================================================
// conv2m: merged [z0: adiff only (-I folded) | k0p partials].
// z1 (x0t transpose) DELETED: k3_bf now builds its B-operand directly from
// row-major x0 via the k3_mfma-proven register transpose (x0 is L3-warm).
// Diag fold is branchless on NAMED members (runtime float4 indexing = UB,
// caused the 5.3125 failures in r4/r5/r6/r21).
// ============================================================================
__global__ __launch_bounds__(512) void conv2m(
    const float* __restrict__ A0, const float* __restrict__ x0,
    const float* __restrict__ u0,
    const float* __restrict__ t0, const float* __restrict__ t1,
    const float* __restrict__ Qw, const float* __restrict__ Kw,
    const float* __restrict__ Tw,
    char* __restrict__ adiff,
    float* __restrict__ P)
{
  const int bid = blockIdx.x;
  const int t = threadIdx.x;
  __shared__ float vb[4][4][32];                // k0p

  if (bid < 768) {
    // ---------- z0: adiff only; 16 rows x 4-float chunks ----------
    const int bc = bid >> 3, tile = bid & 7;
    const int r0 = tile*64;
    const size_t abase = (size_t)bc*LL*LL;
    char* ad = adiff + (size_t)bc*LL*LL*2;
    const int q4 = t & 127, rg = t >> 7;       // 4-float chunk; 4 row-groups
    const int base = r0 + rg*16;
    float4 prev = *reinterpret_cast<const float4*>(A0 + abase + (size_t)base*LL + q4*4);
#pragma unroll 4
    for (int i = 0; i < 16; ++i) {
      int gr = base + i;
      float4 cur;
      if (gr + 1 < LL)
        cur = *reinterpret_cast<const float4*>(A0 + abase + (size_t)(gr+1)*LL + q4*4);
      else cur = prev;
      float4 d;
      if (gr < LL-1) d = f4sub(cur, prev);
      else           d = make_float4(0.f,0.f,0.f,0.f);
      // fold -I into adiff; row 511 -> -e511. Branchless on NAMED members.
      if ((gr >> 2) == q4) {
        int e = gr & 3;
        d.x -= (e == 0) ? 1.0f : 0.0f;
        d.y -= (e == 1) ? 1.0f : 0.0f;
        d.z -= (e == 2) ? 1.0f : 0.0f;
        d.w -= (e == 3) ? 1.0f : 0.0f;
      }
      ushort4 pk;
      pk.x = f2bf(d.x); pk.y = f2bf(d.y); pk.z = f2bf(d.z); pk.w = f2bf(d.w);
      *reinterpret_cast<ushort4*>(ad + (size_t)gr*1024 + q4*8) = pk;
      prev = cur;
    }
  } else {
    // ---------- k0p: split-K partial matvecs ----------
    const int idx = bid - 768;
    const int bg = idx & 7;
    const int rem = idx >> 3;
    const int c  = rem % 3;
    const int ec = rem / 3;
    const int b0 = bg*4;
    const int e0 = ec*32;
    const int f  = t;
    {
      int vec = f >> 7, j = (f >> 5) & 3, e = f & 31;
      int bb = b0 + j;
      float v;
      if      (vec == 0) v = t0[bb*EE + e0 + e];
      else if (vec == 1) v = t1[bb*EE + e0 + e];
      else if (vec == 2) v = x0[((size_t)(bb*CC + c)*LL + (LL-1))*EE + e0 + e];
      else               v = u0[(size_t)(bb*CC + c)*EE + e0 + e];
      vb[vec][j][e] = v;
    }
    __syncthreads();
    const float* twp = Tw + (size_t)c*EE*EE + (size_t)e0*EE + f;
    const float* qwp = Qw + (size_t)c*EE*EE + (size_t)e0*EE + f;
    const float* kwp = Kw + (size_t)c*EE*EE + (size_t)e0*EE + f;
    float aT0[4]={0,0,0,0}, aT1[4]={0,0,0,0}, aQ[4]={0,0,0,0}, aK[4]={0,0,0,0};
#pragma unroll 8
    for (int e = 0; e < 32; ++e) {
      float wt = twp[(size_t)e*EE];
      float wq = qwp[(size_t)e*EE];
      float wk = kwp[(size_t)e*EE];
#pragma unroll
      for (int j = 0; j < 4; ++j) {
        aT0[j] = fmaf(vb[0][j][e], wt, aT0[j]);
        aT1[j] = fmaf(vb[1][j][e], wt, aT1[j]);
        aQ[j]  = fmaf(vb[2][j][e], wq, aQ[j]);
        aK[j]  = fmaf(vb[3][j][e], wk, aK[j]);
      }
    }
#pragma unroll
    for (int j = 0; j < 4; ++j) {
      int cb = c*BB + b0 + j;
      P[(((size_t)0*NEC + ec)*96 + cb)*EE + f] = aT0[j];
      P[(((size_t)1*NEC + ec)*96 + cb)*EE + f] = aT1[j];
      P[(((size_t)2*NEC + ec)*96 + cb)*EE + f] = aQ[j];
      P[(((size_t)3*NEC + ec)*96 + cb)*EE + f] = aK[j];
    }
  }
}

// ============ k0c: combine partials -> gt, ws_w (R24-VERBATIM, proven) ============
__global__ __launch_bounds__(512) void k0c(
    const float* __restrict__ P,
    const float* __restrict__ Qb, const float* __restrict__ Kb,
    float* __restrict__ gtbuf, float* __restrict__ ws_w)
{
  const int bc = blockIdx.x;
  const int b = bc / CC, c = bc % CC;
  const int cb = c*BB + b;
  const int f = threadIdx.x;
  const int wid = f >> 6, lane = f & 63;
  __shared__ float red[8][3];
  float aT0=0.f, aT1=0.f, aQ=0.f, aK=0.f;
#pragma unroll
  for (int ec = 0; ec < NEC; ++ec) {
    aT0 += P[(((size_t)0*NEC + ec)*96 + cb)*EE + f];
    aT1 += P[(((size_t)1*NEC + ec)*96 + cb)*EE + f];
    aQ  += P[(((size_t)2*NEC + ec)*96 + cb)*EE + f];
    aK  += P[(((size_t)3*NEC + ec)*96 + cb)*EE + f];
  }
  float Qv = aQ*aT0 + Qb[c*EE + f];
  float Kv = aK*aT1 + Kb[c*EE + f];
  gtbuf[(size_t)cb*EE + f] = Qv*Kv*aT1;
  float pn = wred_sum(aT0*aT1);
  float p0 = wred_sum(aT0*aT0);
  float p1 = wred_sum(aT1*aT1);
  if (lane == 0) { red[wid][0]=pn; red[wid][1]=p0; red[wid][2]=p1; }
  __syncthreads();
  if (f == 0) {
    float sn=0.f, s0=0.f, s1=0.f;
    for (int i=0;i<8;++i){ sn+=red[i][0]; s0+=red[i][1]; s1+=red[i][2]; }
    ws_w[bc] = sn / sqrtf(s0 + s1);
  }
}

// ============ k1: split-precision MFMA h (R9-VERBATIM, proven) ============
__global__ __launch_bounds__(256) void k1_h(
    const float* __restrict__ Vw, const float* __restrict__ gtbuf,
    float* __restrict__ ws_h)
{
  const int nt = blockIdx.x;
  const int c  = blockIdx.y;
  const int n0 = nt*128;
  const int t = threadIdx.x, lane = t & 63, w = t >> 6;
  __shared__ __align__(16) char AgtH[32*1024];
  __shared__ __align__(16) char AgtL[32*1024];
  __shared__ __align__(16) char BvH[128*128];
  __shared__ __align__(16) char BvL[128*128];
  {
    int row = t >> 3, sl = t & 7;
    const float* src = gtbuf + ((size_t)(c*BB + row))*EE + sl*64;
#pragma unroll
    for (int c3 = 0; c3 < 8; ++c3) {
      float4 a = *reinterpret_cast<const float4*>(src + c3*8);
      float4 b = *reinterpret_cast<const float4*>(src + c3*8 + 4);
      ushort4 h0,h1,l0,l1;
      split1(a.x,h0.x,l0.x); split1(a.y,h0.y,l0.y); split1(a.z,h0.z,l0.z); split1(a.w,h0.w,l0.w);
      split1(b.x,h1.x,l1.x); split1(b.y,h1.y,l1.y); split1(b.z,h1.z,l1.z); split1(b.w,h1.w,l1.w);
      int off = row*1024 + sl*128 + ((c3 ^ (row & 7)) << 4);
      *reinterpret_cast<ushort4*>(AgtH + off)     = h0;
      *reinterpret_cast<ushort4*>(AgtH + off + 8) = h1;
      *reinterpret_cast<ushort4*>(AgtL + off)     = l0;
      *reinterpret_cast<ushort4*>(AgtL + off + 8) = l1;
    }
  }
  f32x4 acc[2][2];
#pragma unroll
  for (int mi=0; mi<2; ++mi)
#pragma unroll
    for (int ni=0; ni<2; ++ni) acc[mi][ni] = (f32x4){0.f,0.f,0.f,0.f};

  for (int kk = 0; kk < 8; ++kk) {
    __syncthreads();
    {
      int nl = t >> 1, half = t & 1;
      const float* src = Vw + (size_t)c*EE*EE + (size_t)(n0+nl)*EE + kk*64 + half*32;
#pragma unroll
      for (int q = 0; q < 4; ++q) {
        float4 a = *reinterpret_cast<const float4*>(src + q*8);
        float4 b = *reinterpret_cast<const float4*>(src + q*8 + 4);
        int c3 = half*4 + q;
        ushort4 h0,h1,l0,l1;
        split1(a.x,h0.x,l0.x); split1(a.y,h0.y,l0.y); split1(a.z,h0.z,l0.z); split1(a.w,h0.w,l0.w);
        split1(b.x,h1.x,l1.x); split1(b.y,h1.y,l1.y); split1(b.z,h1.z,l1.z); split1(b.w,h1.w,l1.w);
        int off = nl*128 + ((c3 ^ (nl & 7)) << 4);
        *reinterpret_cast<ushort4*>(BvH + off)     = h0;
        *reinterpret_cast<ushort4*>(BvH + off + 8) = h1;
        *reinterpret_cast<ushort4*>(BvL + off)     = l0;
        *reinterpret_cast<ushort4*>(BvL + off + 8) = l1;
      }
    }
    __syncthreads();
    bf16x8 afH[2][2], afL[2][2], bfH[2][2], bfL[2][2];
#pragma unroll
    for (int mi=0; mi<2; ++mi)
#pragma unroll
      for (int ks=0; ks<2; ++ks) {
        int row = mi*16 + (lane & 15);
        int c3 = ks*4 + (lane >> 4);
        int off = row*1024 + kk*128 + ((c3 ^ (row & 7)) << 4);
        afH[mi][ks] = *reinterpret_cast<const bf16x8*>(AgtH + off);
        afL[mi][ks] = *reinterpret_cast<const bf16x8*>(AgtL + off);
      }
#pragma unroll
    for (int ni=0; ni<2; ++ni)
#pragma unroll
      for (int ks=0; ks<2; ++ks) {
        int n = w*32 + ni*16 + (lane & 15);
        int c3 = ks*4 + (lane >> 4);
        int off = n*128 + ((c3 ^ (n & 7)) << 4);
        bfH[ni][ks] = *reinterpret_cast<const bf16x8*>(BvH + off);
        bfL[ni][ks] = *reinterpret_cast<const bf16x8*>(BvL + off);
      }
#pragma unroll
    for (int mi=0; mi<2; ++mi)
#pragma unroll
      for (int ni=0; ni<2; ++ni)
#pragma unroll
        for (int ks=0; ks<2; ++ks) {
          acc[mi][ni] = __builtin_amdgcn_mfma_f32_16x16x32_bf16(afH[mi][ks], bfH[ni][ks], acc[mi][ni], 0, 0, 0);
          acc[mi][ni] = __builtin_amdgcn_mfma_f32_16x16x32_bf16(afH[mi][ks], bfL[ni][ks], acc[mi][ni], 0, 0, 0);
          acc[mi][ni] = __builtin_amdgcn_mfma_f32_16x16x32_bf16(afL[mi][ks], bfH[ni][ks], acc[mi][ni], 0, 0, 0);
        }
  }
#pragma unroll
  for (int mi=0; mi<2; ++mi)
#pragma unroll
    for (int ni=0; ni<2; ++ni)
#pragma unroll
      for (int r=0; r<4; ++r) {
        int b = mi*16 + (lane >> 4)*4 + r;
        int e = n0 + w*32 + ni*16 + (lane & 15);
        ws_h[((size_t)(b*CC + c))*EE + e] = acc[mi][ni][r];
      }
}

// ============ k2f: merged softmax+stats; writes out2 row 511 (R25-VERBATIM) ============
__global__ __launch_bounds__(512) void k2f(
    const float* __restrict__ A0, const float* __restrict__ x0,
    const float* __restrict__ u0,
    const float* __restrict__ ws_h, const float* __restrict__ ws_w,
    float* __restrict__ out1, float* __restrict__ out2, float* __restrict__ out3)
{
  const int bc = blockIdx.x;
  const int tid = threadIdx.x, wid = tid >> 6, lane = tid & 63;
  __shared__ __align__(16) float hb[EE], sb[LL], a0r0[LL], a0r3[LL];
  __shared__ float red[8];
  __shared__ float partl[4][12][128];
  const size_t abase = (size_t)bc*LL*LL;
  const size_t xbase = (size_t)bc*LL*EE;
  hb[tid]   = ws_h[(size_t)bc*EE + tid];
  a0r0[tid] = A0[abase + tid];
  a0r3[tid] = A0[abase + (size_t)(LL-1)*LL + tid];
  __syncthreads();
  const float4 h0 = *reinterpret_cast<const float4*>(&hb[lane*8]);
  const float4 h1 = *reinterpret_cast<const float4*>(&hb[lane*8+4]);
  for (int l = wid; l < LL; l += 8) {
    const float4* xr = reinterpret_cast<const float4*>(x0 + xbase + (size_t)l*EE);
    float4 v0 = xr[lane*2], v1 = xr[lane*2+1];
    float acc = v0.x*h0.x + v0.y*h0.y + v0.z*h0.z + v0.w*h0.w
              + v1.x*h1.x + v1.y*h1.y + v1.z*h1.z + v1.w*h1.w;
    acc = wred_sum(acc);
    if (lane == 0) sb[l] = acc;
  }
  __syncthreads();
  float v = sb[tid];
  float mx = wred_max(v);
  if (lane == 0) red[wid] = mx;
  __syncthreads();
  mx = red[0];
#pragma unroll
  for (int i = 1; i < 8; ++i) mx = fmaxf(mx, red[i]);
  float ev = __expf(v - mx);
  float sm = wred_sum(ev);
  __syncthreads();
  if (lane == 0) red[wid] = sm;
  __syncthreads();
  float tot = 0.f;
#pragma unroll
  for (int i = 0; i < 8; ++i) tot += red[i];
  float qk = ev / tot;
  sb[tid] = qk;
  st_nt_f(out1 + abase + (size_t)(LL-1)*LL + tid, qk - a0r0[tid]);
  __syncthreads();
  const int mg = tid >> 7, cg = tid & 127;
  float4 aq = make_float4(0,0,0,0), a0s = make_float4(0,0,0,0), a3s = make_float4(0,0,0,0);
#pragma unroll 4
  for (int i = 0; i < 128; ++i) {
    int m = mg*128 + i;
    float4 xv = *reinterpret_cast<const float4*>(x0 + xbase + (size_t)m*EE + cg*4);
    float qm = sb[m], z0 = a0r0[m], z3 = a0r3[m];
    f4ma(aq, qm, xv); f4ma(a0s, z0, xv); f4ma(a3s, z3, xv);
  }
#pragma unroll
  for (int k = 0; k < 4; ++k) {
    partl[mg][0+k][cg] = (&aq.x)[k];
    partl[mg][4+k][cg] = (&a0s.x)[k];
    partl[mg][8+k][cg] = (&a3s.x)[k];
  }
  __syncthreads();
  if (mg == 0) {
    float wv = ws_w[bc];
    float4 uv  = *reinterpret_cast<const float4*>(u0 + (size_t)bc*EE + cg*4);
    float4 x51 = *reinterpret_cast<const float4*>(x0 + xbase + (size_t)(LL-1)*EE + cg*4);
    float4 qx4, o3;
#pragma unroll
    for (int k = 0; k < 4; ++k) {
      float q = 0.f, y0 = 0.f, y3 = 0.f;
#pragma unroll
      for (int g = 0; g < 4; ++g) {
        q  += partl[g][0+k][cg];
        y0 += partl[g][4+k][cg];
        y3 += partl[g][8+k][cg];
      }
      (&qx4.x)[k] = q;
      (&o3.x)[k] = wv * ((y3 - y0 + q) * (1.f/(float)LL) - (&uv.x)[k]);
    }
    // out2 row 511 = qx - x0[511] (exact f32); k3_bf skips this row
    st_nt_f4(out2 + xbase + (size_t)(LL-1)*EE + cg*4, f4sub(qx4, x51));
    st_nt_f4(out3 + (size_t)bc*EE + cg*4, o3);
  }
}

// ============ k3_bf: (D-I)@x0 + balanced out1 reconstruction ============
// B-operand now staged directly from row-major x0 via the k3_mfma-proven
// register transpose (x0 is L3-warm); x0t intermediate deleted.
#define ASTR 80
__global__ __launch_bounds__(256) void k3_bf(
    const char* __restrict__ adiff, const float* __restrict__ x0,
    const float* __restrict__ A0,
    float* __restrict__ out1, float* __restrict__ out2)
{
  const int bc = blockIdx.y;
  const int rt = blockIdx.x >> 2, nt = blockIdx.x & 3;
  const int r0 = rt*128, n0b = nt*128;
  const int t = threadIdx.x;
  const int lane = t & 63, wid = t >> 6;
  const int wr = wid >> 1, wc = wid & 1;
  __shared__ __align__(16) char As[128*ASTR];
  __shared__ __align__(16) char Bs[128*ASTR];
  __shared__ __align__(16) float zr[LL];
  const char* ad = adiff + (size_t)bc*LL*LL*2;
  const size_t abase = (size_t)bc*LL*LL;
  const size_t xbase = (size_t)bc*LL*EE;
  zr[t]       = A0[abase + t];
  zr[t + 256] = A0[abase + t + 256];
  f32x4 acc[4][4];
#pragma unroll
  for (int mi=0; mi<4; ++mi)
#pragma unroll
    for (int ni=0; ni<4; ++ni) acc[mi][ni] = (f32x4){0.f,0.f,0.f,0.f};

  const int bkl = (t & 7) * 4;     // k-offset within 32
  const int bn0 = (t >> 3) * 4;    // n-offset within 128

  for (int k0 = 0; k0 < LL; k0 += 32) {
    __syncthreads();
#pragma unroll
    for (int i = 0; i < 2; ++i) {
      int idx = i*256 + t;
      int row = idx >> 2, c = idx & 3;
      int4 v = *reinterpret_cast<const int4*>(ad + (size_t)(r0+row)*1024 + k0*2 + c*16);
      *reinterpret_cast<int4*>(As + row*ASTR + c*16) = v;
    }
    {
      // Bs staging from row-major f32 x0 (k3_mfma-VERBATIM register transpose)
      float xq[4][4];
#pragma unroll
      for (int i = 0; i < 4; ++i)
        *reinterpret_cast<float4*>(xq[i]) =
          *reinterpret_cast<const float4*>(x0 + xbase + (size_t)(k0+bkl+i)*EE + n0b + bn0);
#pragma unroll
      for (int j = 0; j < 4; ++j) {
        int n = bn0 + j;
        ushort4 pk;
        pk.x = f2bf(xq[0][j]); pk.y = f2bf(xq[1][j]);
        pk.z = f2bf(xq[2][j]); pk.w = f2bf(xq[3][j]);
        int kb = (bkl*2) ^ (((n >> 2) & 3) << 4);
        *reinterpret_cast<ushort4*>(Bs + n*ASTR + kb) = pk;
      }
    }
    __syncthreads();
    bf16x8 af[4], bfv[4];
#pragma unroll
    for (int mi=0; mi<4; ++mi) {
      int row = wr*64 + mi*16 + (lane & 15);
      af[mi] = *reinterpret_cast<const bf16x8*>(As + row*ASTR + ((lane>>4)*16));
    }
#pragma unroll
    for (int ni=0; ni<4; ++ni) {
      int n = wc*64 + ni*16 + (lane & 15);
      int kb = ((lane>>4)*16) ^ (((n >> 2) & 3) << 4);
      bfv[ni] = *reinterpret_cast<const bf16x8*>(Bs + n*ASTR + kb);
    }
#pragma unroll
    for (int mi=0; mi<4; ++mi)
#pragma unroll
      for (int ni=0; ni<4; ++ni)
        acc[mi][ni] = __builtin_amdgcn_mfma_f32_16x16x32_bf16(af[mi], bfv[ni], acc[mi][ni], 0, 0, 0);
    // balanced out1 reconstruction: this block owns slabs where ((k0>>5)&3)==nt
    if (((k0 >> 5) & 3) == nt) {
      const int c4 = (t & 7) * 4;
      const int gcol0 = k0 + c4;
      const float4 zz = *reinterpret_cast<const float4*>(&zr[gcol0]);
#pragma unroll
      for (int rr = 0; rr < 4; ++rr) {
        int row = rr*32 + (t >> 3);
        int gr = r0 + row;
        if (gr < LL-1) {
          ushort4 ap = *reinterpret_cast<const ushort4*>(As + row*ASTR + c4*2);
          float4 o;
          o.x = bf2f(ap.x); o.y = bf2f(ap.y); o.z = bf2f(ap.z); o.w = bf2f(ap.w);
          int e = gr - gcol0;
          o.x += (e == 0) ? 1.0f : 0.0f;
          o.y += (e == 1) ? 1.0f : 0.0f;
          o.z += (e == 2) ? 1.0f : 0.0f;
          o.w += (e == 3) ? 1.0f : 0.0f;
          st_nt_f4(out1 + abase + (size_t)gr*LL + gcol0, f4sub(o, zz));
        }
      }
    }
  }
  // epilogue: out2 = acc; row 511 is written by k2f (skip here)
#pragma unroll
  for (int mi=0; mi<4; ++mi)
#pragma unroll
    for (int r=0; r<4; ++r) {
      int grow = r0 + wr*64 + mi*16 + (lane>>4)*4 + r;
      if (grow >= LL-1) continue;
      const size_t rowoff = xbase + (size_t)grow*EE;
#pragma unroll
      for (int ni=0; ni<4; ++ni) {
        int gcol = n0b + wc*64 + ni*16 + (lane & 15);
        st_nt_f(out2 + rowoff + gcol, acc[mi][ni][r]);
      }
    }
}

// ============ kA_fused + k3_mfma: R3-VERBATIM fallback path ============
__global__ __launch_bounds__(512) void kA_fused(
    const float* __restrict__ A0, const float* __restrict__ x0,
    const float* __restrict__ u0,
    const float* __restrict__ t0, const float* __restrict__ t1,
    const float* __restrict__ Qw, const float* __restrict__ Qb,
    const float* __restrict__ Vw,
    const float* __restrict__ Kw, const float* __restrict__ Kb,
    const float* __restrict__ Tw,
    float* __restrict__ ws_qx, float* __restrict__ out1, float* __restrict__ out3)
{
  const int bc = blockIdx.x;
  const int b = bc / CC, c = bc % CC;
  const int tid = threadIdx.x;
  const int wid = tid >> 6, lane = tid & 63;
  __shared__ __align__(16) float t0v[EE], t1v[EE], xl[EE], uv[EE], gt[EE];
  __shared__ __align__(16) float hb[EE], sb[LL], a0r0[LL], a0r3[LL];
  __shared__ float red[3][8];
  __shared__ float wsh;
  const size_t abase = (size_t)bc*LL*LL;
  const size_t xbase = (size_t)bc*LL*EE;

  t0v[tid] = t0[b*EE + tid];
  t1v[tid] = t1[b*EE + tid];
  xl[tid]  = x0[xbase + (size_t)(LL-1)*EE + tid];
  uv[tid]  = u0[(size_t)bc*EE + tid];
  a0r0[tid] = A0[abase + tid];
  a0r3[tid] = A0[abase + (size_t)(LL-1)*LL + tid];
  __syncthreads();

  const int f = tid;
  const float* twp = Tw + (size_t)c*EE*EE + f;
  const float* qwp = Qw + (size_t)c*EE*EE + f;
  const float* kwp = Kw + (size_t)c*EE*EE + f;
  float aT0 = 0.f, aT1 = 0.f, aQ = 0.f, aK = 0.f;
  for (int e = 0; e < EE; ++e) {
    float wt = twp[(size_t)e*EE];
    aT0 = fmaf(t0v[e], wt, aT0);
    aT1 = fmaf(t1v[e], wt, aT1);
    aQ  = fmaf(xl[e],  qwp[(size_t)e*EE], aQ);
    aK  = fmaf(uv[e],  kwp[(size_t)e*EE], aK);
  }
  float Qv = aQ*aT0 + Qb[c*EE + f];
  float Kv = aK*aT1 + Kb[c*EE + f];
  gt[f] = Qv*Kv*aT1;

  float pn = wred_sum(aT0*aT1);
  float p0 = wred_sum(aT0*aT0);
  float p1 = wred_sum(aT1*aT1);
  if (lane == 0) { red[0][wid]=pn; red[1][wid]=p0; red[2][wid]=p1; }
  __syncthreads();
  if (tid == 0) {
    float sn=0.f, s0=0.f, s1=0.f;
    for (int i=0;i<8;++i){ sn+=red[0][i]; s0+=red[1][i]; s1+=red[2][i]; }
    wsh = sn / sqrtf(s0 + s1);
  }
  {
    const float4 g0 = *reinterpret_cast<const float4*>(&gt[lane*8]);
    const float4 g1 = *reinterpret_cast<const float4*>(&gt[lane*8+4]);
    for (int r = wid; r < EE; r += 8) {
      const float4* vr = reinterpret_cast<const float4*>(Vw + ((size_t)c*EE + r)*EE);
      float4 v0 = vr[lane*2], v1 = vr[lane*2+1];
      float acc = v0.x*g0.x + v0.y*g0.y + v0.z*g0.z + v0.w*g0.w
                + v1.x*g1.x + v1.y*g1.y + v1.z*g1.z + v1.w*g1.w;
      acc = wred_sum(acc);
      if (lane == 0) hb[r] = acc;
    }
  }
  __syncthreads();

  {
    const float4 h0 = *reinterpret_cast<const float4*>(&hb[lane*8]);
    const float4 h1 = *reinterpret_cast<const float4*>(&hb[lane*8+4]);
    for (int l = wid; l < LL; l += 8) {
      const float4* xr = reinterpret_cast<const float4*>(x0 + xbase + (size_t)l*EE);
      float4 v0 = xr[lane*2], v1 = xr[lane*2+1];
      float acc = v0.x*h0.x + v0.y*h0.y + v0.z*h0.z + v0.w*h0.w
                + v1.x*h1.x + v1.y*h1.y + v1.z*h1.z + v1.w*h1.w;
      acc = wred_sum(acc);
      if (lane == 0) sb[l] = acc;
    }
  }
  __syncthreads();

  float v = sb[tid];
  float mx = wred_max(v);
  if (lane == 0) red[0][wid] = mx;
  __syncthreads();
  mx = red[0][0];
#pragma unroll
  for (int i = 1; i < 8; ++i) mx = fmaxf(mx, red[0][i]);
  float ev = __expf(v - mx);
  float sm = wred_sum(ev);
  __syncthreads();
  if (lane == 0) red[0][wid] = sm;
  __syncthreads();
  float tot = 0.f;
#pragma unroll
  for (int i = 0; i < 8; ++i) tot += red[0][i];
  float qk = ev / tot;
  sb[tid] = qk;
  out1[abase + (size_t)(LL-1)*LL + tid] = qk - a0r0[tid];
  __syncthreads();

  float qx=0.f, y0=0.f, y3=0.f;
  for (int m = 0; m < LL; ++m) {
    float xm = x0[xbase + (size_t)m*EE + tid];
    qx = fmaf(sb[m],   xm, qx);
    y0 = fmaf(a0r0[m], xm, y0);
    y3 = fmaf(a0r3[m], xm, y3);
  }
  ws_qx[(size_t)bc*EE + tid] = qx;
  float mean = (y3 - y0 + qx) * (1.f/(float)LL);
  out3[(size_t)bc*EE + tid] = wsh * (mean - uv[tid]);
}

__global__ __launch_bounds__(256) void k3_mfma(
    const float* __restrict__ A0, const float* __restrict__ x0,
    const float* __restrict__ ws_qx,
    float* __restrict__ out1, float* __restrict__ out2)
{
  const int bc = blockIdx.y;
  const int rt = blockIdx.x >> 2, nt = blockIdx.x & 3;
  const int r0 = rt*128, n0b = nt*128;
  const int t = threadIdx.x;
  const int lane = t & 63, wid = t >> 6;
  const int wr = wid >> 1, wc = wid & 1;
  __shared__ __align__(16) char As[128*ASTR];
  __shared__ __align__(16) char Bs[128*ASTR];
  const size_t abase = (size_t)bc*LL*LL;
  const size_t xbase = (size_t)bc*LL*EE;
  f32x4 acc[4][4];
#pragma unroll
  for (int mi=0; mi<4; ++mi)
#pragma unroll
    for (int ni=0; ni<4; ++ni) acc[mi][ni] = (f32x4){0.f,0.f,0.f,0.f};
  const int bkl = (t & 7) * 4;
  const int bn0 = (t >> 3) * 4;
  for (int k0 = 0; k0 < LL; k0 += 32) {
    __syncthreads();
#pragma unroll
    for (int i = 0; i < 4; ++i) {
      int idx = i*256 + t;
      int row = idx >> 3, kq = idx & 7;
      int gr = r0 + row;
      int gr1 = (gr+1 > LL-1) ? (LL-1) : (gr+1);
      float4 va = *reinterpret_cast<const float4*>(A0 + abase + (size_t)gr *LL + k0 + kq*4);
      float4 vb = *reinterpret_cast<const float4*>(A0 + abase + (size_t)gr1*LL + k0 + kq*4);
      ushort4 pk;
      pk.x = f2bf(vb.x - va.x); pk.y = f2bf(vb.y - va.y);
      pk.z = f2bf(vb.z - va.z); pk.w = f2bf(vb.w - va.w);
      *reinterpret_cast<ushort4*>(As + row*ASTR + kq*8) = pk;
      if (nt == 0 && gr < LL-1) {
        float4 az = *reinterpret_cast<const float4*>(A0 + abase + k0 + kq*4);
        float4 o = make_float4(vb.x - az.x - va.x, vb.y - az.y - va.y,
                               vb.z - az.z - va.z, vb.w - az.w - va.w);
        *reinterpret_cast<float4*>(out1 + abase + (size_t)gr*LL + k0 + kq*4) = o;
      }
    }
    {
      float xq[4][4];
#pragma unroll
      for (int i = 0; i < 4; ++i)
        *reinterpret_cast<float4*>(xq[i]) =
          *reinterpret_cast<const float4*>(x0 + xbase + (size_t)(k0+bkl+i)*EE + n0b + bn0);
#pragma unroll
      for (int j = 0; j < 4; ++j) {
        int n = bn0 + j;
        ushort4 pk;
        pk.x = f2bf(xq[0][j]); pk.y = f2bf(xq[1][j]);
        pk.z = f2bf(xq[2][j]); pk.w = f2bf(xq[3][j]);
        int kb = (bkl*2) ^ (((n >> 2) & 3) << 4);
        *reinterpret_cast<ushort4*>(Bs + n*ASTR + kb) = pk;
      }
    }
    __syncthreads();
    bf16x8 af[4], bfv[4];
#pragma unroll
    for (int mi=0; mi<4; ++mi) {
      int row = wr*64 + mi*16 + (lane & 15);
      af[mi] = *reinterpret_cast<const bf16x8*>(As + row*ASTR + ((lane>>4)*16));
    }
#pragma unroll
    for (int ni=0; ni<4; ++ni) {
      int n = wc*64 + ni*16 + (lane & 15);
      int kb = ((lane>>4)*16) ^ (((n >> 2) & 3) << 4);
      bfv[ni] = *reinterpret_cast<const bf16x8*>(Bs + n*ASTR + kb);
    }
#pragma unroll
    for (int mi=0; mi<4; ++mi)
#pragma unroll
      for (int ni=0; ni<4; ++ni)
        acc[mi][ni] = __builtin_amdgcn_mfma_f32_16x16x32_bf16(af[mi], bfv[ni], acc[mi][ni], 0, 0, 0);
  }
#pragma unroll
  for (int mi=0; mi<4; ++mi)
#pragma unroll
    for (int r=0; r<4; ++r) {
      int grow = r0 + wr*64 + mi*16 + (lane>>4)*4 + r;
      const size_t rowoff = xbase + (size_t)grow*EE;
#pragma unroll
      for (int ni=0; ni<4; ++ni) {
        int gcol = n0b + wc*64 + ni*16 + (lane & 15);
        float xv = x0[rowoff + gcol];
        float val;
        if (grow == LL-1) val = ws_qx[(size_t)bc*EE + gcol] - xv;
        else              val = acc[mi][ni][r] - xv;
        out2[rowoff + gcol] = val;
      }
    }
}

extern "C" void kernel_launch(void* const* d_in, const int* in_sizes, int n_in,
                              void* d_out, int out_size, void* d_ws, size_t ws_size,
                              hipStream_t stream)
{
  const float* A0 = (const float*)d_in[0];
  const float* x0 = (const float*)d_in[1];
  const float* u0 = (const float*)d_in[2];
  const float* t0 = (const float*)d_in[3];
  const float* t1 = (const float*)d_in[4];
  const float* Qw = (const float*)d_in[5];
  const float* Qb = (const float*)d_in[6];
  const float* Vw = (const float*)d_in[7];
  // d_in[8] = V_bias: zeros + softmax-invariant; skipped.
  const float* Kw = (const float*)d_in[9];
  const float* Kb = (const float*)d_in[10];
  const float* Tw = (const float*)d_in[11];
  // d_in[12] = T_bias: unused by the reference.

  char*  wsb    = (char*)d_ws;
  float* ws_qx  = (float*)(wsb + WSB_QX);
  float* ws_h   = (float*)(wsb + WSB_H);
  float* ws_w   = (float*)(wsb + WSB_W);

  float* out1 = (float*)d_out;
  float* out2 = out1 + O2_OFF;
  float* out3 = out1 + O3_OFF;
  float* gtbuf = out3;   // out3 region doubles as gt scratch (overwritten by k2f)
  float* pscr  = out2;   // out2 region doubles as k0 partial scratch (overwritten by k3_bf)

  const bool fast = ws_size >= WS_FAST_NEED;

  if (fast) {
    char* adiff = wsb + WSB_ADIFF;
    conv2m<<<1152, 512, 0, stream>>>(A0, x0, u0, t0, t1, Qw, Kw, Tw,
                                     adiff, pscr);
    k0c<<<NBC, 512, 0, stream>>>(pscr, Qb, Kb, gtbuf, ws_w);
    k1_h<<<dim3(4, 3), 256, 0, stream>>>(Vw, gtbuf, ws_h);
    k2f<<<NBC, 512, 0, stream>>>(A0, x0, u0, ws_h, ws_w, out1, out2, out3);
    k3_bf<<<dim3(16, NBC), 256, 0, stream>>>(adiff, x0, A0, out1, out2);
  } else {
    kA_fused<<<NBC, 512, 0, stream>>>(A0, x0, u0, t0, t1, Qw, Qb, Vw, Kw, Kb, Tw,
                                      ws_qx, out1, out3);
    k3_mfma<<<dim3(16, NBC), 256, 0, stream>>>(A0, x0, ws_qx, out1, out2);
  }
}